// Round 13
// baseline (150.740 us; speedup 1.0000x reference)
//
#include <hip/hip_runtime.h>
#include <hip/hip_bf16.h>

#define C_DIM 512
#define B_DIM 8
#define T_DIM 16
#define ND_DIM 32
#define NPTS 512   /* T*ND */
#define ROWS 4096  /* B*NPTS */
#define KSZ 7
#define TOUT 10
#define NEG_SLOPE 0.01f
#define LN_EPS 1e-5f

// ---------------- Kernel 1: row L2-normalize ----------------
__global__ __launch_bounds__(256) void norm_kernel(const float* __restrict__ feat,
                                                   float* __restrict__ nrm) {
    int row = blockIdx.x;                  // 0..4095
    int tid = threadIdx.x;
    const float* f = feat + (size_t)row * C_DIM;
    float* o = nrm + (size_t)row * C_DIM;
    float v0 = f[tid];
    float v1 = f[tid + 256];
    float ss = v0 * v0 + v1 * v1;
    #pragma unroll
    for (int off = 32; off > 0; off >>= 1) ss += __shfl_down(ss, off, 64);
    __shared__ float wsum[4];
    int wid = tid >> 6, lane = tid & 63;
    if (lane == 0) wsum[wid] = ss;
    __syncthreads();
    float tot = wsum[0] + wsum[1] + wsum[2] + wsum[3];
    float inv = 1.0f / fmaxf(sqrtf(tot), 1e-12f);
    o[tid] = v0 * inv;
    o[tid + 256] = v1 * inv;
}

// ---------------- Kernel 2a: K-split partial GEMM ----------------
// part[kz][b][row][col] += over k in [kz*256, kz*256+256):
//   (nrm[b][row][k] * wd[k]) * nrm[b][col][k]
// Tile 128x128, 256 threads, 8x8/thread (strided 16), BK=16, double-buffered LDS.
__global__ __launch_bounds__(256, 1) void gemm_part_kernel(const float* __restrict__ nrm,
                                                           const float* __restrict__ W,
                                                           float* __restrict__ part) {
    __shared__ __align__(16) float As[2][128][20];
    __shared__ __align__(16) float Bs[2][128][20];
    __shared__ float wd[256];
    const int tid = threadIdx.x;
    const int tx = tid & 15, ty = tid >> 4;
    const int b = blockIdx.z >> 1, kz = blockIdx.z & 1;
    const int row0 = blockIdx.y * 128, col0 = blockIdx.x * 128;
    const int kbase = kz * 256;
    const float* __restrict__ Nb = nrm + (size_t)b * NPTS * C_DIM;

    wd[tid] = W[(size_t)(kbase + tid) * (C_DIM + 1)];
    __syncthreads();

    const int sr = tid >> 1;          // staged row/col 0..127
    const int kh = (tid & 1) * 8;     // k-half 0 or 8

    // stage step 0 into buf 0
    {
        const float* ga = Nb + (size_t)(row0 + sr) * C_DIM + kbase + kh;
        const float* gb = Nb + (size_t)(col0 + sr) * C_DIM + kbase + kh;
        float4 a0 = *(const float4*)ga, a1 = *(const float4*)(ga + 4);
        float4 b0 = *(const float4*)gb, b1 = *(const float4*)(gb + 4);
        float4 w0 = *(const float4*)&wd[kh], w1 = *(const float4*)&wd[kh + 4];
        a0.x *= w0.x; a0.y *= w0.y; a0.z *= w0.z; a0.w *= w0.w;
        a1.x *= w1.x; a1.y *= w1.y; a1.z *= w1.z; a1.w *= w1.w;
        *(float4*)&As[0][sr][kh] = a0; *(float4*)&As[0][sr][kh + 4] = a1;
        *(float4*)&Bs[0][sr][kh] = b0; *(float4*)&Bs[0][sr][kh + 4] = b1;
    }

    float acc[8][8] = {};
    #pragma unroll 1
    for (int step = 0; step < 16; ++step) {
        __syncthreads();
        const int buf = step & 1;
        if (step + 1 < 16) {            // stage next into buf^1 (overlaps compute)
            const int koff = (step + 1) * 16;
            const float* ga = Nb + (size_t)(row0 + sr) * C_DIM + kbase + koff + kh;
            const float* gb = Nb + (size_t)(col0 + sr) * C_DIM + kbase + koff + kh;
            float4 a0 = *(const float4*)ga, a1 = *(const float4*)(ga + 4);
            float4 b0 = *(const float4*)gb, b1 = *(const float4*)(gb + 4);
            float4 w0 = *(const float4*)&wd[koff + kh], w1 = *(const float4*)&wd[koff + kh + 4];
            a0.x *= w0.x; a0.y *= w0.y; a0.z *= w0.z; a0.w *= w0.w;
            a1.x *= w1.x; a1.y *= w1.y; a1.z *= w1.z; a1.w *= w1.w;
            *(float4*)&As[buf ^ 1][sr][kh] = a0; *(float4*)&As[buf ^ 1][sr][kh + 4] = a1;
            *(float4*)&Bs[buf ^ 1][sr][kh] = b0; *(float4*)&Bs[buf ^ 1][sr][kh + 4] = b1;
        }
        #pragma unroll
        for (int k4 = 0; k4 < 4; ++k4) {
            float4 av[8], bv[8];
            #pragma unroll
            for (int i = 0; i < 8; i++) av[i] = *(const float4*)&As[buf][ty + 16 * i][k4 * 4];
            #pragma unroll
            for (int j = 0; j < 8; j++) bv[j] = *(const float4*)&Bs[buf][tx + 16 * j][k4 * 4];
            #pragma unroll
            for (int i = 0; i < 8; i++)
                #pragma unroll
                for (int j = 0; j < 8; j++)
                    acc[i][j] += av[i].x * bv[j].x + av[i].y * bv[j].y
                               + av[i].z * bv[j].z + av[i].w * bv[j].w;
        }
    }

    float* Cb = part + ((size_t)(kz * B_DIM + b) * NPTS + row0) * NPTS + col0;
    #pragma unroll
    for (int i = 0; i < 8; i++)
        #pragma unroll
        for (int j = 0; j < 8; j++)
            Cb[(size_t)(ty + 16 * i) * NPTS + tx + 16 * j] = acc[i][j];
}

// ---------------- Kernel 2b: reduce K-split partials + per-32-group argmax ----------------
__global__ __launch_bounds__(256) void reduce_argmax_kernel(const float* __restrict__ part,
                                                            int* __restrict__ idxg) {
    const int bn = blockIdx.x * 4 + (threadIdx.x >> 6);   // 0..4095
    const int lane = threadIdx.x & 63;
    const float* p0 = part + (size_t)bn * NPTS + lane * 8;
    const float* p1 = part + (size_t)(ROWS + bn) * NPTS + lane * 8;
    float4 x0 = *(const float4*)p0, x1 = *(const float4*)(p0 + 4);
    float4 y0 = *(const float4*)p1, y1 = *(const float4*)(p1 + 4);
    float v[8] = { x0.x + y0.x, x0.y + y0.y, x0.z + y0.z, x0.w + y0.w,
                   x1.x + y1.x, x1.y + y1.y, x1.z + y1.z, x1.w + y1.w };
    float best = v[0];
    int bc = lane * 8;                       // global column index
    #pragma unroll
    for (int c = 1; c < 8; c++) {
        if (v[c] > best) { best = v[c]; bc = lane * 8 + c; }   // first max wins
    }
    #pragma unroll
    for (int m = 1; m < 4; m <<= 1) {        // reduce across the 4 lanes of each 32-col group
        float ov = __shfl_xor(best, m, 64);
        int oc = __shfl_xor(bc, m, 64);
        if (ov > best || (ov == best && oc < bc)) { best = ov; bc = oc; }
    }
    if ((lane & 3) == 0) idxg[(size_t)bn * T_DIM + (lane >> 2)] = bc & 31;
}

// ---------------- Kernel 2-fallback: fused 64x64 GEMM+argmax (small ws) ----------------
__global__ __launch_bounds__(256) void gemm_argmax_kernel(const float* __restrict__ nrm,
                                                          const float* __restrict__ W,
                                                          int* __restrict__ idxg) {
    __shared__ __align__(16) float As[16][68];
    __shared__ __align__(16) float Bs[16][68];
    __shared__ float Cs[64][65];
    __shared__ float wd[C_DIM];
    const int tid = threadIdx.x;
    const int tx = tid & 15, ty = tid >> 4;
    const int b = blockIdx.z;
    const int row0 = blockIdx.y * 64, col0 = blockIdx.x * 64;
    const float* Nb = nrm + (size_t)b * NPTS * C_DIM;

    wd[tid]       = W[(size_t)tid * (C_DIM + 1)];
    wd[tid + 256] = W[(size_t)(tid + 256) * (C_DIM + 1)];
    __syncthreads();

    float acc[4][4] = {};
    for (int k0 = 0; k0 < C_DIM; k0 += 16) {
        #pragma unroll
        for (int e = 0; e < 4; e++) {
            int idx = tid + e * 256;
            int m = idx >> 4, kk = idx & 15;
            As[kk][m] = Nb[(size_t)(row0 + m) * C_DIM + k0 + kk] * wd[k0 + kk];
            Bs[kk][m] = Nb[(size_t)(col0 + m) * C_DIM + k0 + kk];
        }
        __syncthreads();
        #pragma unroll
        for (int kk = 0; kk < 16; kk++) {
            float4 a4 = *(const float4*)&As[kk][ty * 4];
            float4 b4 = *(const float4*)&Bs[kk][tx * 4];
            float av[4] = {a4.x, a4.y, a4.z, a4.w};
            float bv[4] = {b4.x, b4.y, b4.z, b4.w};
            #pragma unroll
            for (int i = 0; i < 4; i++)
                #pragma unroll
                for (int j = 0; j < 4; j++)
                    acc[i][j] += av[i] * bv[j];
        }
        __syncthreads();
    }
    #pragma unroll
    for (int i = 0; i < 4; i++)
        #pragma unroll
        for (int j = 0; j < 4; j++)
            Cs[ty * 4 + i][tx * 4 + j] = acc[i][j];
    __syncthreads();
    if (tid < 128) {
        int r = tid >> 1, g = tid & 1;
        const float* crow = &Cs[r][g * 32];
        float best = crow[0];
        int bi = 0;
        for (int j = 1; j < 32; j++) {
            float v = crow[j];
            if (v > best) { best = v; bi = j; }
        }
        int n_glob = b * NPTS + row0 + r;
        int tg = (col0 >> 5) + g;
        idxg[(size_t)n_glob * T_DIM + tg] = bi;
    }
}

// ---------------- Kernel 3: wave-per-row gather + conv + LN + leaky + mean ----------------
__global__ __launch_bounds__(256, 2) void fuse_kernel(const int* __restrict__ idxg,
                                                      const float* __restrict__ lf,
                                                      const float* __restrict__ cw,
                                                      const float* __restrict__ cb,
                                                      const float* __restrict__ gamma,
                                                      const float* __restrict__ beta,
                                                      float* __restrict__ out) {
    const int wave = threadIdx.x >> 6;        // 0..3
    const int lane = threadIdx.x & 63;
    const int bn = blockIdx.x * 4 + wave;     // 0..4095
    const int b = bn >> 9;
    const int c0 = lane * 8;

    float x[T_DIM][8];
    #pragma unroll
    for (int t = 0; t < T_DIM; t++) {
        int idx = idxg[(size_t)bn * T_DIM + t];
        const float* p = lf + (((size_t)(b * T_DIM + t)) * ND_DIM + idx) * C_DIM + c0;
        float4 lo = *(const float4*)p;
        float4 hi = *(const float4*)(p + 4);
        x[t][0] = lo.x; x[t][1] = lo.y; x[t][2] = lo.z; x[t][3] = lo.w;
        x[t][4] = hi.x; x[t][5] = hi.y; x[t][6] = hi.z; x[t][7] = hi.w;
    }

    float w[KSZ][8];
    #pragma unroll
    for (int c = 0; c < 8; c++)
        #pragma unroll
        for (int k = 0; k < KSZ; k++)
            w[k][c] = cw[(size_t)(c0 + c) * KSZ + k];
    float bias[8], g[8], be[8];
    {
        float4 b_lo = *(const float4*)&cb[c0],    b_hi = *(const float4*)&cb[c0 + 4];
        float4 g_lo = *(const float4*)&gamma[c0], g_hi = *(const float4*)&gamma[c0 + 4];
        float4 e_lo = *(const float4*)&beta[c0],  e_hi = *(const float4*)&beta[c0 + 4];
        bias[0]=b_lo.x; bias[1]=b_lo.y; bias[2]=b_lo.z; bias[3]=b_lo.w;
        bias[4]=b_hi.x; bias[5]=b_hi.y; bias[6]=b_hi.z; bias[7]=b_hi.w;
        g[0]=g_lo.x; g[1]=g_lo.y; g[2]=g_lo.z; g[3]=g_lo.w;
        g[4]=g_hi.x; g[5]=g_hi.y; g[6]=g_hi.z; g[7]=g_hi.w;
        be[0]=e_lo.x; be[1]=e_lo.y; be[2]=e_lo.z; be[3]=e_lo.w;
        be[4]=e_hi.x; be[5]=e_hi.y; be[6]=e_hi.z; be[7]=e_hi.w;
    }

    float accum[8] = {};
    #pragma unroll
    for (int tau = 0; tau < TOUT; tau++) {
        float y[8];
        #pragma unroll
        for (int c = 0; c < 8; c++) {
            float v = bias[c];
            #pragma unroll
            for (int k = 0; k < KSZ; k++) v += x[tau + k][c] * w[k][c];
            y[c] = v;
        }
        float s = 0.f, q = 0.f;
        #pragma unroll
        for (int c = 0; c < 8; c++) { s += y[c]; q += y[c] * y[c]; }
        #pragma unroll
        for (int m = 1; m < 64; m <<= 1) {
            s += __shfl_xor(s, m, 64);
            q += __shfl_xor(q, m, 64);
        }
        float mu = s * (1.0f / 512.0f);
        float var = q * (1.0f / 512.0f) - mu * mu;
        float rs = rsqrtf(var + LN_EPS);
        #pragma unroll
        for (int c = 0; c < 8; c++) {
            float ln = (y[c] - mu) * rs * g[c] + be[c];
            accum[c] += ln >= 0.f ? ln : NEG_SLOPE * ln;
        }
    }
    float* o = out + (size_t)bn * C_DIM + c0;
    float4 r_lo = make_float4(accum[0]*0.1f, accum[1]*0.1f, accum[2]*0.1f, accum[3]*0.1f);
    float4 r_hi = make_float4(accum[4]*0.1f, accum[5]*0.1f, accum[6]*0.1f, accum[7]*0.1f);
    *(float4*)o = r_lo;
    *(float4*)(o + 4) = r_hi;
}

// ---------------- diagnostic sentinel (only runs if ws is too small) ----------------
__global__ void sentinel_kernel(float* out, int n, float val) {
    int i = blockIdx.x * 256 + threadIdx.x;
    if (i < n) out[i] = val;
}

extern "C" void kernel_launch(void* const* d_in, const int* in_sizes, int n_in,
                              void* d_out, int out_size, void* d_ws, size_t ws_size,
                              hipStream_t stream) {
    const float* local_feat = (const float*)d_in[0];
    // d_in[1] = global_feat (unused), d_in[2] = pos (unused)
    const float* W       = (const float*)d_in[3];
    const float* conv_w  = (const float*)d_in[4];
    const float* conv_b  = (const float*)d_in[5];
    const float* ln_g    = (const float*)d_in[6];
    const float* ln_b    = (const float*)d_in[7];
    float* out = (float*)d_out;   // reference output dtype is float32

    (void)hipGetLastError();      // clear any stale error

    const size_t nrm_bytes  = (size_t)ROWS * C_DIM * sizeof(float);        // 8 MB
    const size_t part_bytes = (size_t)2 * ROWS * NPTS * sizeof(float);     // 16 MB
    const size_t idx_bytes  = (size_t)ROWS * T_DIM * sizeof(int);          // 256 KB

    if (d_ws == nullptr || ws_size < nrm_bytes + idx_bytes) {
        float val = 512.0f + (float)(ws_size >> 20);
        sentinel_kernel<<<(out_size + 255) / 256, 256, 0, stream>>>(out, out_size, val);
        return;
    }

    float* nrm = (float*)d_ws;

    norm_kernel<<<ROWS, 256, 0, stream>>>(local_feat, nrm);

    int* idxg;
    if (ws_size >= nrm_bytes + part_bytes + idx_bytes) {
        // fast path: K-split partial GEMM + reduce/argmax
        float* part = (float*)((char*)d_ws + nrm_bytes);
        idxg = (int*)((char*)d_ws + nrm_bytes + part_bytes);
        gemm_part_kernel<<<dim3(NPTS / 128, NPTS / 128, B_DIM * 2), 256, 0, stream>>>(nrm, W, part);
        reduce_argmax_kernel<<<ROWS / 4, 256, 0, stream>>>(part, idxg);
    } else {
        // fallback: fused 64x64 GEMM+argmax
        idxg = (int*)((char*)d_ws + nrm_bytes);
        gemm_argmax_kernel<<<dim3(NPTS / 64, NPTS / 64, B_DIM), 256, 0, stream>>>(nrm, W, idxg);
    }

    fuse_kernel<<<ROWS / 4, 256, 0, stream>>>(idxg, local_feat, conv_w, conv_b,
                                              ln_g, ln_b, out);

    if (hipGetLastError() != hipSuccess) {
        hipMemsetAsync(d_out, 0x42, (size_t)out_size * 2, stream);
    }
}